// Round 7
// baseline (126.319 us; speedup 1.0000x reference)
//
#include <hip/hip_runtime.h>
#include <hip/hip_bf16.h>

#define NND   325
#define SEQ   12
#define NT    3900            // 325*12
#define KP    352             // padded j (11 chunks of 32)
#define NC    11              // k-chunks of 32
#define CHUNK_SHORTS 12288    // 384 n-rows * 32 j (plain, chunk-major)
#define MROWS 48              // gt rows per cheb block (4 g-slices), 3 exact m-tiles
#define NTILE 22              // n-tiles of 16 (352/16)
#define TROW  328             // n-minor Y/Z: shorts per t-row (325 + 3 pad, 41 octs)
#define GROW  3936            // shorts per g-slice (12 * 328)

typedef __attribute__((ext_vector_type(8))) short short8;
typedef __attribute__((ext_vector_type(4))) float floatx4;

static __device__ __forceinline__ unsigned short f2bf(float f) {
    unsigned int u = __float_as_uint(f);
    unsigned int r = (u + 0x7fffu + ((u >> 16) & 1u)) >> 16;  // RNE
    return (unsigned short)r;
}

// A-image index (shorts): [MROWS][KP], 16B slot XOR-swizzled by row pair
static __device__ __forceinline__ int xi(int m, int j) {
    int slot = (j >> 3) ^ ((m >> 1) & 3);
    return m * KP + slot * 8 + (j & 7);
}
// mix-kernel swizzle (row stride 384 B)
static __device__ __forceinline__ int swz(int n) {
    return ((n & 7) ^ ((n >> 3) & 7)) << 4;
}

// ---- setup: d^{-1/2} ----
__global__ void calc_dis(const float* __restrict__ adj, float* __restrict__ dis) {
    int i = blockIdx.x;
    const float* row = adj + (size_t)i * NND;
    float s = 0.f;
    for (int j = threadIdx.x; j < NND; j += 64) s += row[j];
    for (int o = 32; o; o >>= 1) s += __shfl_down(s, o);
    if (threadIdx.x == 0) dis[i] = (s > 0.f) ? rsqrtf(s) : 0.f;
}

// ---- setup: L chunk-major plain bf16 [c][n<384][32 j] (zero-padded) ----
__global__ void build_L2(const float* __restrict__ adj, const float* __restrict__ dis,
                         unsigned short* __restrict__ Lg2) {
    int s = blockIdx.x * 256 + threadIdx.x;
    if (s >= NC * CHUNK_SHORTS) return;
    int c = s / CHUNK_SHORTS, r = s - c * CHUNK_SHORTS;
    int n = r >> 5, w = r & 31;
    int j = c * 32 + w;
    float v = 0.f;
    if (n < NND && j < NND) {
        float a = adj[(size_t)n * NND + j];
        v = ((n == j) ? 1.f : 0.f) - dis[n] * a * dis[j];
    }
    Lg2[s] = f2bf(v);
}

// ---- setup: folded weights as swizzled bf16 image A[d][k], k=kind*64+c ----
__global__ void build_wswz(const float* __restrict__ W, unsigned short* __restrict__ wswz) {
    int idx = blockIdx.x * 256 + threadIdx.x;
    if (idx >= 64 * 192) return;
    int d = idx / 192, k = idx - d * 192;
    int kind = k >> 6, c = k & 63;
    float wv = W[kind * 4096 + c * 64 + d];
    float w;
    if (kind == 0)      w = wv - W[2 * 4096 + c * 64 + d];
    else if (kind == 1) w = wv;
    else                w = 2.f * wv;
    int byte = d * 384 + ((2 * k) ^ swz(d));
    wswz[byte >> 1] = f2bf(w);
}

// ---- Chebyshev double L-apply, operand-swapped streamed-L version.
// Block: 48 gt-rows (4 g-slices), 512 threads (8 waves), 66 KB LDS.
// GEMMs compute C[n][m] = sum_j L[n,j] * S[m,j] with A = streamed L row-frags
// (1KB coalesced global bursts, L2-hot) and B = Xs/Ys LDS row-frags.
// C-layout (4 consecutive n per lane) -> store_acc is 9 ds_write_b64 into the
// natural [m][n] image; copy_out is ds_read_b128 + 16B coalesced store into
// the n-minor global layout [g][t*328+n].
__global__ __launch_bounds__(512, 4) void cheb_mfma(
        const float* __restrict__ x,
        const unsigned short* __restrict__ Lg2,
        unsigned short* __restrict__ Yg,
        unsigned short* __restrict__ Zg) {
    __shared__ __align__(16) unsigned short Xs[MROWS * KP];   // 33792 B
    __shared__ __align__(16) unsigned short Ys[MROWS * KP];   // 33792 B

    const int tid = threadIdx.x;
    int bid = blockIdx.x;
    bid = (bid & 7) * 128 + (bid >> 3);       // XCD swizzle (1024 = 8*128)
    const int g0 = bid * 4;

    const int w  = tid >> 6;
    const int l  = tid & 63;
    const int lm = l & 15, lg = l >> 4;
    const int ap = (lm >> 1) & 3;             // B-slot XOR for row m=mt*16+lm

    // per-wave L A-frag base addresses, n-tiles 3w..3w+2 (image rows <384 ok)
    const unsigned short* lp[3];
    #pragma unroll
    for (int i = 0; i < 3; ++i) {
        int nrow = (w * 3 + i) * 16 + lm;
        lp[i] = Lg2 + (size_t)nrow * 32 + lg * 8;   // + c*CHUNK_SHORTS per chunk
    }
    const int nown = (w * 3 + 2 < NTILE) ? 3 : (NTILE - w * 3 < 0 ? 0 : NTILE - w * 3);

    // ---- stage X (and zero pad cols 325..351) ----
    for (int i = tid; i < MROWS * 27; i += 512) {
        int m = i / 27, j = 325 + (i - (i / 27) * 27);
        Xs[xi(m, j)] = 0;
    }
    const float4* xb = (const float4*)(x + (size_t)g0 * NT);
    for (int i = tid; i < 3900; i += 512) {
        float4 v = xb[i];
        int f = i * 4;
        int gl = f / NT;
        int rem = f - gl * NT;
        int j = rem / SEQ;
        int t0 = rem - j * SEQ;       // 0,4,8
        int m = gl * SEQ + t0;
        Xs[xi(m + 0, j)] = f2bf(v.x);
        Xs[xi(m + 1, j)] = f2bf(v.y);
        Xs[xi(m + 2, j)] = f2bf(v.z);
        Xs[xi(m + 3, j)] = f2bf(v.w);
    }
    __syncthreads();

    floatx4 acc[3][3];                // [n-local][mt]

    auto zero_acc = [&]() {
        #pragma unroll
        for (int a = 0; a < 3; ++a)
            #pragma unroll
            for (int b2 = 0; b2 < 3; ++b2) acc[a][b2] = (floatx4){0.f, 0.f, 0.f, 0.f};
    };

    auto gemm = [&](const unsigned short* Bimg) {
        #pragma unroll
        for (int c = 0; c < NC; ++c) {
            short8 lf[3];
            #pragma unroll
            for (int i = 0; i < 3; ++i)
                if (i < nown)
                    lf[i] = *(const short8*)(lp[i] + (size_t)c * CHUNK_SHORTS);
            short8 bf[3];
            #pragma unroll
            for (int mt = 0; mt < 3; ++mt) {
                int m = mt * 16 + lm;
                int slot = (c * 4 + lg) ^ ap;
                bf[mt] = *(const short8*)&Bimg[m * KP + slot * 8];
            }
            #pragma unroll
            for (int i = 0; i < 3; ++i)
                if (i < nown)
                    #pragma unroll
                    for (int mt = 0; mt < 3; ++mt)
                        acc[i][mt] = __builtin_amdgcn_mfma_f32_16x16x32_bf16(
                            lf[i], bf[mt], acc[i][mt], 0, 0, 0);
        }
    };

    // C[n][m]: lane holds rows n0+0..3 (n0=(3w+i)*16+lg*4), col m=mt*16+lm
    // -> 4 consecutive n in image row m: one ds_write_b64 each.
    auto store_acc = [&](unsigned short* img) {
        #pragma unroll
        for (int i = 0; i < 3; ++i) {
            if (i < nown) {
                int n0 = (w * 3 + i) * 16 + lg * 4;
                #pragma unroll
                for (int mt = 0; mt < 3; ++mt) {
                    int m = mt * 16 + lm;
                    int slot = (n0 >> 3) ^ ((m >> 1) & 3);
                    ushort4 u;
                    u.x = f2bf(acc[i][mt][0]);
                    u.y = f2bf(acc[i][mt][1]);
                    u.z = f2bf(acc[i][mt][2]);
                    u.w = f2bf(acc[i][mt][3]);
                    *(ushort4*)&img[m * KP + slot * 8 + (n0 & 7)] = u;
                }
            }
        }
    };

    // n-minor global: dst[g][t*328 + n], one b128 LDS read + 16B store per oct
    auto copy_out = [&](const unsigned short* img, unsigned short* dst) {
        for (int i = tid; i < 4 * SEQ * 41; i += 512) {   // 1968
            int gl = i / 492;
            int r2 = i - gl * 492;
            int t = r2 / 41;
            int oct = r2 - t * 41;
            int m = gl * SEQ + t;
            int slot = oct ^ ((m >> 1) & 3);
            short8 v = *(const short8*)&img[m * KP + slot * 8];
            *(short8*)&dst[(size_t)(g0 + gl) * GROW + t * TROW + oct * 8] = v;
        }
    };

    // ---- GEMM1: Y = L * X  (stored as natural [m][n] image) ----
    zero_acc();
    gemm(Xs);
    store_acc(Ys);
    __syncthreads();
    copy_out(Ys, Yg);

    // ---- GEMM2: Z = L * Y ----
    zero_acc();
    gemm(Ys);
    store_acc(Xs);                    // reuse Xs as Z staging
    __syncthreads();
    copy_out(Xs, Zg);
}

// ---- Phase B: out = A(64x192) x B(192 x 96nt) per (b, nt-tile), MFMA ----
__global__ __launch_bounds__(256) void mix_mfma(
        const float* __restrict__ x,
        const unsigned short* __restrict__ Yg,
        const unsigned short* __restrict__ Zg,
        const unsigned short* __restrict__ wswz,
        const float* __restrict__ bias,
        float* __restrict__ out) {
    __shared__ unsigned short Bl[96 * 192];   // 36864 B swizzled [n][k]
    __shared__ unsigned short Al[64 * 192];   // 24576 B swizzled [d][k]
    const int tid = threadIdx.x;
    int lin = blockIdx.x;
    lin = (lin & 7) * 328 + (lin >> 3);       // XCD swizzle (2624 = 8*328)
    const int b = lin / 41;
    const int nt0 = (lin - b * 41) * 96;
    const bool tail = (nt0 + 96 > NT);

    for (int i = tid; i < 1536; i += 256)
        *(short8*)((char*)Al + i * 16) = *(const short8*)((const char*)wswz + i * 16);

    // rows 0..63 from x (fp32 -> bf16), flat-nt addressing
    for (int i = tid; i < 768; i += 256) {
        int r = i / 12, ch = i - r * 12;
        int nt = nt0 + ch * 8;
        const float* sp = x + ((size_t)b * 64 + r) * NT + nt;
        float f[8];
        if (!tail || nt + 8 <= NT) {
            float4 v0 = *(const float4*)sp;
            float4 v1 = *(const float4*)(sp + 4);
            f[0] = v0.x; f[1] = v0.y; f[2] = v0.z; f[3] = v0.w;
            f[4] = v1.x; f[5] = v1.y; f[6] = v1.z; f[7] = v1.w;
        } else {
            #pragma unroll
            for (int jj = 0; jj < 8; ++jj) f[jj] = (nt + jj < NT) ? sp[jj] : 0.f;
        }
        int k2 = 2 * r;
        #pragma unroll
        for (int jj = 0; jj < 8; ++jj) {
            int n = ch * 8 + jj;
            *(unsigned short*)((char*)Bl + n * 384 + (k2 ^ swz(n))) = f2bf(f[jj]);
        }
    }
    // rows 64..191 from Y'/Z' (n-minor layout [g][t*328+n]); pads are zeros
    const int nn0 = nt0 / 12;                 // multiple of 8
    for (int i = tid; i < 1536; i += 256) {
        int r = 64 + i / 12, t = i % 12;
        const unsigned short* base = (r < 128) ? Yg : Zg;
        const unsigned short* sp = base + ((size_t)b * 64 + (r & 63)) * GROW + t * TROW + nn0;
        ushort4 v0 = *(const ushort4*)sp;
        ushort4 v1 = *(const ushort4*)(sp + 4);
        unsigned short f[8];
        f[0] = v0.x; f[1] = v0.y; f[2] = v0.z; f[3] = v0.w;
        f[4] = v1.x; f[5] = v1.y; f[6] = v1.z; f[7] = v1.w;
        int k2 = 2 * r;
        #pragma unroll
        for (int jj = 0; jj < 8; ++jj) {
            int q = jj * 12 + t;              // flat col within tile
            *(unsigned short*)((char*)Bl + q * 384 + (k2 ^ swz(q))) = f[jj];
        }
    }
    __syncthreads();

    const int w = __builtin_amdgcn_readfirstlane(tid >> 6);
    const int l = tid & 63;
    const int lm = l & 15, lg = l >> 4;

    floatx4 acc[6];
    #pragma unroll
    for (int i = 0; i < 6; ++i) acc[i] = (floatx4){0.f, 0.f, 0.f, 0.f};

    const int arow = w * 16 + lm;
    const char* Ab = (const char*)Al + arow * 384;
    #pragma unroll
    for (int ks = 0; ks < 6; ++ks) {
        const int k2 = (ks * 32 + lg * 8) * 2;
        short8 a = *(const short8*)(Ab + (k2 ^ swz(arow)));
        #pragma unroll
        for (int ni = 0; ni < 6; ++ni) {
            int n = ni * 16 + lm;
            short8 bb = *(const short8*)((const char*)Bl + n * 384 + (k2 ^ swz(n)));
            acc[ni] = __builtin_amdgcn_mfma_f32_16x16x32_bf16(a, bb, acc[ni], 0, 0, 0);
        }
    }

    float br[4];
    #pragma unroll
    for (int j = 0; j < 4; ++j) br[j] = bias[w * 16 + lg * 4 + j];
    #pragma unroll
    for (int ni = 0; ni < 6; ++ni) {
        int nt = nt0 + ni * 16 + lm;
        if (nt < NT) {
            float* op = out + ((size_t)b * 64 + w * 16 + lg * 4) * NT + nt;
            #pragma unroll
            for (int j = 0; j < 4; ++j) op[(size_t)j * NT] = acc[ni][j] + br[j];
        }
    }
}

extern "C" void kernel_launch(void* const* d_in, const int* in_sizes, int n_in,
                              void* d_out, int out_size, void* d_ws, size_t ws_size,
                              hipStream_t stream) {
    const float* x   = (const float*)d_in[0];
    const float* adj = (const float*)d_in[1];
    const float* W   = (const float*)d_in[2];
    const float* b   = (const float*)d_in[3];
    float* out = (float*)d_out;

    char* ws = (char*)d_ws;
    // layout (bytes):
    //   0        : dis   (325 f32, pad 1312)
    //   1312     : Lg2   (11*12288 bf16 = 270336)
    //   271648   : wswz  (12288 bf16 = 24576)
    //   296224   : Y'    (4096*3936 bf16 = 32243712)
    //   32539936 : Z'    (32243712) -> end 64783648 (~61.8 MiB)
    float* dis           = (float*)(ws + 0);
    unsigned short* Lg2  = (unsigned short*)(ws + 1312);
    unsigned short* wswz = (unsigned short*)(ws + 271648);
    unsigned short* Yg   = (unsigned short*)(ws + 296224);
    unsigned short* Zg   = (unsigned short*)(ws + 32539936);

    calc_dis<<<NND, 64, 0, stream>>>(adj, dis);
    build_L2<<<(NC * CHUNK_SHORTS + 255) / 256, 256, 0, stream>>>(adj, dis, Lg2);
    build_wswz<<<48, 256, 0, stream>>>(W, wswz);
    cheb_mfma<<<1024, 512, 0, stream>>>(x, Lg2, Yg, Zg);
    mix_mfma<<<2624, 256, 0, stream>>>(x, Yg, Zg, wswz, b, out);
}